// Round 4
// baseline (389.335 us; speedup 1.0000x reference)
//
#include <hip/hip_runtime.h>
#include <hip/hip_bf16.h>

// Problem constants
#define BATCH 2
#define SEQ   2048
#define EMB   1024
#define NH    16
#define HD    64
#define MROWS (BATCH*SEQ)   // 4096
#define NX    (MROWS*EMB)   // 4194304
#define NW    (EMB*EMB)     // 1048576 = 2^20

using f32x4  = __attribute__((ext_vector_type(4))) float;
using bf16x8 = __attribute__((ext_vector_type(8))) short;

#define GLOBAL_AS(p) ((const __attribute__((address_space(1))) void*)(p))
#define LDS_AS(p)    ((__attribute__((address_space(3))) void*)(p))

#define ROPE_L2 0.4152410118609203f    // log2(10000)/32
#define QSCALE  0.045084220027780106f  // (1/sqrt(E)) * log2(e)

// ---------------------------------------------------------------------------
// Fused f32->bf16 cast of x and the 4 weight matrices (Wq,Wk,Wv stacked),
// PLUS (tail blocks) the RoPE cos/sin table and the combine-flag zeroing.
// ---------------------------------------------------------------------------
__global__ void fused_cast_kernel(const float* __restrict__ x,
                                  const float* __restrict__ Wq,
                                  const float* __restrict__ Wk,
                                  const float* __restrict__ Wv,
                                  const float* __restrict__ Wo,
                                  __hip_bfloat16* __restrict__ xb,
                                  __hip_bfloat16* __restrict__ Wqkvb,
                                  __hip_bfloat16* __restrict__ Wob,
                                  float2* __restrict__ ctab,
                                  uint* __restrict__ Flags) {
    if (blockIdx.x == 4352) {
        // zero the 512 combine handshake flags (only 480 used)
        Flags[threadIdx.x]       = 0;
        Flags[256 + threadIdx.x] = 0;
        return;
    }
    if (blockIdx.x >= 4096) {
        // RoPE table tail: one entry per thread
        int e  = (blockIdx.x - 4096) * 256 + threadIdx.x;   // [0, 65536)
        int s  = e >> 5;
        int ip = e & 31;
        float inv = exp2f(-(float)ip * ROPE_L2);
        float fr  = (float)s * inv;
        float2 cs;
        cs.x = cosf(fr);
        cs.y = sinf(fr);
        ctab[e] = cs;
        return;
    }
    size_t i8 = (size_t)(blockIdx.x * 256 + threadIdx.x) * 8;
    const float* src;
    __hip_bfloat16* dst;
    if (i8 < (size_t)NX) {
        src = x + i8;
        dst = xb + i8;
    } else {
        size_t w = i8 - NX;
        int which = (int)(w >> 20);
        size_t local = w & (NW - 1);
        if (which < 3) {
            src = (which == 0 ? Wq : (which == 1 ? Wk : Wv)) + local;
            dst = Wqkvb + w;
        } else {
            src = Wo + local;
            dst = Wob + local;
        }
    }
    float4 a = *(const float4*)(src);
    float4 b = *(const float4*)(src + 4);
    union { uint4 u; ushort s[8]; } o;
    const float* f = (const float*)&a;
#pragma unroll
    for (int j = 0; j < 4; ++j) {
        __hip_bfloat16 h = __float2bfloat16(f[j]);
        o.s[j] = *(ushort*)&h;
    }
    f = (const float*)&b;
#pragma unroll
    for (int j = 0; j < 4; ++j) {
        __hip_bfloat16 h = __float2bfloat16(f[j]);
        o.s[4 + j] = *(ushort*)&h;
    }
    *(uint4*)dst = o.u;
}

// ---------------------------------------------------------------------------
// Fused QKV GEMM: C[M,3072] = A[M,K] * Wqkv[3072,K]^T, routed to Q/K/V.
// 128x128 tile, BK=64, global_load_lds staging. grid (24,32) = 3 blocks/CU.
// T2 LDS swizzle (pre-swizzled gll SOURCE + XOR read; rule #21 involution).
// RoPE fused into the epilogue for Q/K outputs; Q scaled by QSCALE.
// ---------------------------------------------------------------------------
__global__ __launch_bounds__(256) void gemm_qkv_kernel(
        const __hip_bfloat16* __restrict__ A,
        const __hip_bfloat16* __restrict__ W,
        __hip_bfloat16* __restrict__ Qo,
        __hip_bfloat16* __restrict__ Ko,
        __hip_bfloat16* __restrict__ Vo,
        const float2* __restrict__ ctab, int M, int K) {
    __shared__ __hip_bfloat16 As[128 * 64];
    __shared__ __hip_bfloat16 Bs[128 * 64];

    const int tid  = threadIdx.x;
    const int wave = tid >> 6;
    const int lane = tid & 63;
    const int quad = lane >> 4;
    const int l16  = lane & 15;
    const int m0   = blockIdx.y * 128;
    const int n0   = blockIdx.x * 128;
    const int wm   = (wave >> 1) * 64;
    const int wn   = (wave & 1) * 64;
    const int xr   = l16 & 7;              // read-side XOR factor (row&7)

    f32x4 acc[4][4] = {};

    for (int k0 = 0; k0 < K; k0 += 64) {
#pragma unroll
        for (int it = 0; it < 4; ++it) {
            int flat = (wave * 4 + it) * 64 + lane;
            int row  = flat >> 3;
            int g    = (flat & 7) ^ (row & 7);   // inverse-swizzled source
            const __hip_bfloat16* ga = A + (size_t)(m0 + row) * K + k0 + g * 8;
            const __hip_bfloat16* gb = W + (size_t)(n0 + row) * K + k0 + g * 8;
            __builtin_amdgcn_global_load_lds(GLOBAL_AS(ga),
                LDS_AS(As + (size_t)(wave * 4 + it) * 512), 16, 0, 0);
            __builtin_amdgcn_global_load_lds(GLOBAL_AS(gb),
                LDS_AS(Bs + (size_t)(wave * 4 + it) * 512), 16, 0, 0);
        }
        __syncthreads();

#pragma unroll
        for (int kk = 0; kk < 2; ++kk) {
            const int kg = (kk * 4 + quad) ^ xr;   // swizzled read slot
            bf16x8 af[4], bfr[4];
#pragma unroll
            for (int i = 0; i < 4; ++i) {
                af[i]  = *(const bf16x8*)(&As[(wm + i * 16 + l16) * 64 + kg * 8]);
                bfr[i] = *(const bf16x8*)(&Bs[(wn + i * 16 + l16) * 64 + kg * 8]);
            }
#pragma unroll
            for (int i = 0; i < 4; ++i)
#pragma unroll
                for (int j = 0; j < 4; ++j)
                    acc[i][j] = __builtin_amdgcn_mfma_f32_16x16x32_bf16(
                        af[i], bfr[j], acc[i][j], 0, 0, 0);
        }
        __syncthreads();
    }

    const int tens = n0 >> 10;
    __hip_bfloat16* outp = (tens == 0) ? Qo : ((tens == 1) ? Ko : Vo);
    const int nbase = n0 & 1023;
    if (tens < 2) {
        // Q/K: apply RoPE on fp32 accumulators, then store (Q: * QSCALE)
        const float sgn   = (l16 & 1) ? 1.0f : -1.0f;   // odd: +, even: -
        const float qmul  = (tens == 0) ? QSCALE : 1.0f;
#pragma unroll
        for (int i = 0; i < 4; ++i)
#pragma unroll
            for (int j = 0; j < 4; ++j) {
                int col  = nbase + wn + j * 16 + l16;
                int ip   = ((wn + j * 16 + l16) & 63) >> 1;   // pair index [0,32)
                int row0 = m0 + wm + i * 16 + quad * 4;
#pragma unroll
                for (int rr = 0; rr < 4; ++rr) {
                    float v = acc[i][j][rr];
                    float p = __shfl_xor(v, 1);
                    int sp  = (row0 + rr) & (SEQ - 1);
                    float2 cs = ctab[sp * 32 + ip];
                    float o = (v * cs.x + sgn * p * cs.y) * qmul;
                    outp[(size_t)(row0 + rr) * EMB + col] = __float2bfloat16(o);
                }
            }
    } else {
#pragma unroll
        for (int i = 0; i < 4; ++i)
#pragma unroll
            for (int j = 0; j < 4; ++j) {
                int col  = nbase + wn + j * 16 + l16;
                int row0 = m0 + wm + i * 16 + quad * 4;
#pragma unroll
                for (int rr = 0; rr < 4; ++rr)
                    outp[(size_t)(row0 + rr) * EMB + col] = __float2bfloat16(acc[i][j][rr]);
            }
    }
}

// ---------------------------------------------------------------------------
// O-projection GEMM: C[M,N] = A[M,K] * B[N,K]^T, fp32 out.
// 128x64 tile -> grid (16,32) = 512 blocks = 2/CU. T2 swizzle as in qkv.
// ---------------------------------------------------------------------------
__global__ __launch_bounds__(256) void gemm_oproj_kernel(
        const __hip_bfloat16* __restrict__ A,
        const __hip_bfloat16* __restrict__ Bm,
        float* __restrict__ C, int M, int N, int K) {
    __shared__ __hip_bfloat16 As[128 * 64];
    __shared__ __hip_bfloat16 Bs[64 * 64];

    const int tid  = threadIdx.x;
    const int wave = tid >> 6;
    const int lane = tid & 63;
    const int quad = lane >> 4;
    const int l16  = lane & 15;
    const int m0   = blockIdx.y * 128;
    const int n0   = blockIdx.x * 64;
    const int wm   = (wave >> 1) * 64;
    const int wn   = (wave & 1) * 32;
    const int xr   = l16 & 7;

    f32x4 acc[4][2] = {};

    for (int k0 = 0; k0 < K; k0 += 64) {
#pragma unroll
        for (int it = 0; it < 4; ++it) {
            int flat = (wave * 4 + it) * 64 + lane;
            int row  = flat >> 3;
            int g    = (flat & 7) ^ (row & 7);
            const __hip_bfloat16* ga = A + (size_t)(m0 + row) * K + k0 + g * 8;
            __builtin_amdgcn_global_load_lds(GLOBAL_AS(ga),
                LDS_AS(As + (size_t)(wave * 4 + it) * 512), 16, 0, 0);
        }
#pragma unroll
        for (int it = 0; it < 2; ++it) {
            int flat = (wave * 2 + it) * 64 + lane;
            int row  = flat >> 3;
            int g    = (flat & 7) ^ (row & 7);
            const __hip_bfloat16* gb = Bm + (size_t)(n0 + row) * K + k0 + g * 8;
            __builtin_amdgcn_global_load_lds(GLOBAL_AS(gb),
                LDS_AS(Bs + (size_t)(wave * 2 + it) * 512), 16, 0, 0);
        }
        __syncthreads();

#pragma unroll
        for (int kk = 0; kk < 2; ++kk) {
            const int kg = (kk * 4 + quad) ^ xr;
            bf16x8 af[4], bfr[2];
#pragma unroll
            for (int i = 0; i < 4; ++i)
                af[i] = *(const bf16x8*)(&As[(wm + i * 16 + l16) * 64 + kg * 8]);
#pragma unroll
            for (int j = 0; j < 2; ++j)
                bfr[j] = *(const bf16x8*)(&Bs[(wn + j * 16 + l16) * 64 + kg * 8]);
#pragma unroll
            for (int i = 0; i < 4; ++i)
#pragma unroll
                for (int j = 0; j < 2; ++j)
                    acc[i][j] = __builtin_amdgcn_mfma_f32_16x16x32_bf16(
                        af[i], bfr[j], acc[i][j], 0, 0, 0);
        }
        __syncthreads();
    }

#pragma unroll
    for (int i = 0; i < 4; ++i)
#pragma unroll
        for (int j = 0; j < 2; ++j) {
            int col  = n0 + wn + j * 16 + l16;
            int row0 = m0 + wm + i * 16 + quad * 4;
#pragma unroll
            for (int rr = 0; rr < 4; ++rr)
                C[(size_t)(row0 + rr) * N + col] = acc[i][j][rr];
        }
}

// Single-instruction helpers (T12 recipe; no builtin for cvt_pk on gfx950)
__device__ inline uint cvt_pk_bf16(float lo, float hi) {
    uint r;
    asm("v_cvt_pk_bf16_f32 %0, %1, %2" : "=v"(r) : "v"(lo), "v"(hi));
    return r;
}
__device__ inline float exp2_raw(float x) {
    float r;
    asm("v_exp_f32 %0, %1" : "=v"(r) : "v"(x));
    return r;
}

// ---------------------------------------------------------------------------
// S^T flash attention (causal), fixed-base exp2 softmax (QSCALE*log2e in Q).
// S^T = K·Q^T (operand swap is free: A and B fragment layouts identical).
//
// v4 changes (attacking VALU instruction COUNT, the R3-surviving limiter):
//  * P-pack: v_cvt_pk_bf16_f32 (1 inst/pair, 8/iter) replaces __float2bfloat16
//    RNE emulation (~6 insts/cast, ~96/iter). Same RNE rounding.
//  * exp2: raw v_exp_f32 (1 inst) replaces libm exp2f fixup (~5 insts).
//    Masked lanes (-16384) underflow to 0 correctly.
//  * combine fused in: for qt>=17, the SECOND of the two partial-writing
//    blocks (device-scope atomic handshake per G16) combines + finalizes the
//    tile. q-tile 16 (A p=15, complete k-range) finalizes directly.
//    combine_kernel deleted.
// v3 kept: row-sum via ones-MFMA (of_sum layout = epilogue layout), perm
//    V^T pack, T5 setprio. v2 kept: register-resident P (k-slot permutation
//    invariance), K gll with pre-swizzled source, 1 barrier/tile dbuf.
// Partition: grid (32, B*H) = 1024 blocks:
//   bx<16  (A, p=bx):    q-tile 31-p, k-tiles [0,17)   -> slot 0 (p=15: FINAL)
//   bx>=16 (B, p=bx-16): q-tile 31-p, k-tiles [17,31-p]-> slot 1
//                        then q-tile p, k-tiles [0, p] -> FINAL write
// ---------------------------------------------------------------------------
__global__ __launch_bounds__(256) void attn_mfma_kernel(
        const __hip_bfloat16* __restrict__ Qb,
        const __hip_bfloat16* __restrict__ Kb,
        const __hip_bfloat16* __restrict__ Vb,
        __hip_bfloat16* __restrict__ Attnb,
        __hip_bfloat16* __restrict__ Opart,
        float* __restrict__ Lpart,
        uint* __restrict__ Flags) {
    const int bx   = blockIdx.x;
    const int bh   = blockIdx.y;
    const int b    = bh >> 4;
    const int h    = bh & (NH - 1);
    const int tid  = threadIdx.x;
    const int wave = tid >> 6;
    const int lane = tid & 63;
    const int quad = lane >> 4;
    const int l16  = lane & 15;

    __shared__ __hip_bfloat16 Ks[2][64 * 64];  // 16 KB, XOR col-swizzled, key-major
    __shared__ uint VTs[2][64][33];            // 16.5 KB, packed V^T pairs
    __shared__ uint hsh;                       // handshake broadcast

    const int vtp = tid >> 3;                  // 0..31: key pair (V staging)
    const int sg  = tid & 7;                   // dim group  (V staging)
    const int lr  = lane >> 3;                 // gll: row within 8-row chunk
    const int lg  = (lane & 7) ^ lr;           // pre-swizzled source col group
    const size_t ksrc_lane = (size_t)lr * EMB + lg * 8;

    const __hip_bfloat16* Kbase = Kb + (size_t)b * SEQ * EMB + h * HD;
    const __hip_bfloat16* Vbase = Vb + (size_t)b * SEQ * EMB + h * HD;

    // B-operand of all-ones bf16 (1.0 = 0x3F80) for the row-sum MFMA
    union { uint u[4]; bf16x8 v; } onesu;
    onesu.u[0] = 0x3F803F80u; onesu.u[1] = 0x3F803F80u;
    onesu.u[2] = 0x3F803F80u; onesu.u[3] = 0x3F803F80u;
    const bf16x8 ones = onesu.v;

    const bool isA = (bx < 16);
    const int p   = isA ? bx : bx - 16;
    const int q0  = 31 - p;
    const int k00 = isA ? 0 : 17;
    const int n0s = isA ? 17 : (15 - p);
    const int q1  = p;
    const int n1s = isA ? 0 : (p + 1);

    for (int s = 0; s < 2; ++s) {
        const int qt = s ? q1 : q0;
        const int k0 = s ? 0 : k00;
        const int nt = s ? n1s : n0s;
        if (nt <= 0) continue;               // block-uniform
        // A p=15 covers k-tiles [0,17) for q-tile 16 == complete causal range
        const bool finalSeg = (!isA && s == 1) || (isA && p == 15);
        const int wrow = qt * 64 + wave * 16;

        // LDS handoff: previous segment's readers must finish before the
        // prologue gll below overwrites Ks[0]. Block-uniform path.
        __syncthreads();

        // Q fragments (B operand; layout identical to A): lane = q-row l16
        bf16x8 qf[2];
        {
            const __hip_bfloat16* qp =
                Qb + (size_t)(b * SEQ + wrow + l16) * EMB + h * HD + quad * 8;
            qf[0] = *(const bf16x8*)(qp);
            qf[1] = *(const bf16x8*)(qp + 32);
        }

        f32x4 of[4]  = {};       // O: col d = nb*16+l16, row q = quad*4+r
        f32x4 of_sum = {};       // L: row q = quad*4+r (all l16 identical)

        // prologue: stage tile k0 (V -> regs, K -> LDS buf0 via gll)
        const __hip_bfloat16* kgp = Kbase + (size_t)k0 * 64 * EMB;
        const __hip_bfloat16* vgp = Vbase + (size_t)(k0 * 64 + 2 * vtp) * EMB + sg * 8;
        uint4 vr0 = *(const uint4*)(vgp);
        uint4 vr1 = *(const uint4*)(vgp + EMB);
#pragma unroll
        for (int it = 0; it < 2; ++it)
            __builtin_amdgcn_global_load_lds(
                GLOBAL_AS(kgp + (size_t)(wave * 2 + it) * 8 * EMB + ksrc_lane),
                LDS_AS(&Ks[0][(wave * 2 + it) * 512]), 16, 0, 0);

        for (int i = 0; i < nt; ++i) {
            const int cur = i & 1;
            const int kt  = k0 + i;

            // V^T pack -> LDS: one v_perm_b32 per packed pair
            {
                const uint* v0u = (const uint*)&vr0;
                const uint* v1u = (const uint*)&vr1;
#pragma unroll
                for (int j = 0; j < 4; ++j) {
                    VTs[cur][sg * 8 + 2 * j][vtp] =
                        __builtin_amdgcn_perm(v1u[j], v0u[j], 0x05040100u);
                    VTs[cur][sg * 8 + 2 * j + 1][vtp] =
                        __builtin_amdgcn_perm(v1u[j], v0u[j], 0x07060302u);
                }
            }
            __syncthreads();     // drains gll(i): Ks[cur] + VTs[cur] ready

            if (i + 1 < nt) {    // stage tile i+1; drains at next barrier
                kgp += (size_t)64 * EMB;
                vgp += (size_t)64 * EMB;
                vr0 = *(const uint4*)(vgp);
                vr1 = *(const uint4*)(vgp + EMB);
#pragma unroll
                for (int it = 0; it < 2; ++it)
                    __builtin_amdgcn_global_load_lds(
                        GLOBAL_AS(kgp + (size_t)(wave * 2 + it) * 8 * EMB + ksrc_lane),
                        LDS_AS(&Ks[cur ^ 1][(wave * 2 + it) * 512]), 16, 0, 0);
            }

            // ---- S^T = K·Q^T: sc[mb] covers keys mb*16.. for q = wrow+l16 ----
            const bool diag = (kt == qt);
            const __hip_bfloat16* KsC = Ks[cur];
            f32x4 sc[4];
            __builtin_amdgcn_s_setprio(1);
#pragma unroll
            for (int mb = 0; mb < 4; ++mb) {
                f32x4 a = {};
                if (!(diag && mb > wave)) {
                    int krow = mb * 16 + l16;
#pragma unroll
                    for (int kb = 0; kb < 2; ++kb) {
                        int kg = (kb * 4 + quad) ^ (krow & 7);
                        bf16x8 kf = *(const bf16x8*)(&KsC[krow * 64 + kg * 8]);
                        a = __builtin_amdgcn_mfma_f32_16x16x32_bf16(kf, qf[kb], a, 0, 0, 0);
                    }
                }
                sc[mb] = a;
            }
            __builtin_amdgcn_s_setprio(0);

            // mask: key = mb*16+quad*4+r  vs  q = wave*16+l16 (local offsets)
            if (diag) {
#pragma unroll
                for (int mb = 0; mb < 4; ++mb)
#pragma unroll
                    for (int r = 0; r < 4; ++r)
                        if (mb * 16 + quad * 4 + r > wave * 16 + l16)
                            sc[mb][r] = -16384.0f;
            }

            // ---- p = 2^s via raw v_exp_f32 (row-sum via ones-MFMA below) ----
#pragma unroll
            for (int mb = 0; mb < 4; ++mb)
#pragma unroll
                for (int r = 0; r < 4; ++r)
                    sc[mb][r] = exp2_raw(sc[mb][r]);

            // ---- P stays in registers (k-permuted; matches V pair reads) ----
            bf16x8 pf[2];
            {
                union { uint u[4]; bf16x8 v; } t;
                t.u[0] = cvt_pk_bf16(sc[0][0], sc[0][1]);
                t.u[1] = cvt_pk_bf16(sc[0][2], sc[0][3]);
                t.u[2] = cvt_pk_bf16(sc[1][0], sc[1][1]);
                t.u[3] = cvt_pk_bf16(sc[1][2], sc[1][3]);
                pf[0] = t.v;
                t.u[0] = cvt_pk_bf16(sc[2][0], sc[2][1]);
                t.u[1] = cvt_pk_bf16(sc[2][2], sc[2][3]);
                t.u[2] = cvt_pk_bf16(sc[3][0], sc[3][1]);
                t.u[3] = cvt_pk_bf16(sc[3][2], sc[3][3]);
                pf[1] = t.v;
            }

            // ---- O += P V ; L += P 1 (row-sum on the matrix pipe) ----
            const uint* VT0 = &VTs[cur][0][0];
            __builtin_amdgcn_s_setprio(1);
#pragma unroll
            for (int nb = 0; nb < 4; ++nb) {
                const uint* vrow = VT0 + (size_t)(nb * 16 + l16) * 33;
#pragma unroll
                for (int c = 0; c < 2; ++c) {
                    union { uint u[4]; bf16x8 v; } vf;
                    vf.u[0] = vrow[c * 16 + 2 * quad];
                    vf.u[1] = vrow[c * 16 + 2 * quad + 1];
                    vf.u[2] = vrow[c * 16 + 8 + 2 * quad];
                    vf.u[3] = vrow[c * 16 + 8 + 2 * quad + 1];
                    of[nb] = __builtin_amdgcn_mfma_f32_16x16x32_bf16(
                        pf[c], vf.v, of[nb], 0, 0, 0);
                }
            }
            of_sum = __builtin_amdgcn_mfma_f32_16x16x32_bf16(pf[0], ones, of_sum, 0, 0, 0);
            of_sum = __builtin_amdgcn_mfma_f32_16x16x32_bf16(pf[1], ones, of_sum, 0, 0, 0);
            __builtin_amdgcn_s_setprio(0);
        }

        // ---- segment epilogue: of_sum[r] = L[q = quad*4 + r] directly ----
        const int rl0 = quad * 4;            // local output row base within wave tile
        if (finalSeg) {
            float linv[4];
#pragma unroll
            for (int r = 0; r < 4; ++r)
                linv[r] = 1.0f / of_sum[r];
#pragma unroll
            for (int nb = 0; nb < 4; ++nb)
#pragma unroll
                for (int r = 0; r < 4; ++r) {
                    float v = of[nb][r] * linv[r];
                    Attnb[(size_t)(b * SEQ + wrow + rl0 + r) * EMB + h * HD + nb * 16 + l16] =
                        __float2bfloat16(v);
                }
        } else {
            // qt >= 17 partial path + handshake (G16: fence + device atomic)
            const int slot = isA ? 0 : 1;
            const size_t lbase = ((size_t)slot * 32 + bh) * SEQ + wrow;
            if (l16 == 0) {
#pragma unroll
                for (int r = 0; r < 4; ++r)
                    Lpart[lbase + rl0 + r] = of_sum[r];
            }
#pragma unroll
            for (int nb = 0; nb < 4; ++nb)
#pragma unroll
                for (int r = 0; r < 4; ++r)
                    Opart[(lbase + rl0 + r) * HD + nb * 16 + l16] =
                        __float2bfloat16(of[nb][r]);

            __threadfence();                 // release: our partials visible
            __syncthreads();                 // all threads' fences done
            if (tid == 0)
                hsh = atomicAdd(&Flags[bh * 15 + (qt - 17)], 1u);
            __syncthreads();
            if (hsh == 1) {                  // we are second: combine this tile
                __threadfence();             // acquire: other slot visible
                const int r  = tid >> 2;     // 0..63
                const int cb = tid & 3;      // 0..3 (16-col block)
                const int srow = qt * 64 + r;
                const size_t p0 = ((size_t)bh * SEQ + srow) * HD + cb * 16;
                const size_t p1 = ((size_t)(32 + bh) * SEQ + srow) * HD + cb * 16;
                float lt = Lpart[(size_t)bh * SEQ + srow] +
                           Lpart[(size_t)(32 + bh) * SEQ + srow];
                float inv = 1.0f / lt;
                bf16x8 a0 = *(const bf16x8*)(Opart + p0);
                bf16x8 a1 = *(const bf16x8*)(Opart + p0 + 8);
                bf16x8 b0 = *(const bf16x8*)(Opart + p1);
                bf16x8 b1 = *(const bf16x8*)(Opart + p1 + 8);
                union { uint4 u; ushort w[8]; } o0, o1;
#pragma unroll
                for (int j = 0; j < 8; ++j) {
                    float va = __uint_as_float(((uint)(ushort)a0[j]) << 16) +
                               __uint_as_float(((uint)(ushort)b0[j]) << 16);
                    float vb = __uint_as_float(((uint)(ushort)a1[j]) << 16) +
                               __uint_as_float(((uint)(ushort)b1[j]) << 16);
                    __hip_bfloat16 ha = __float2bfloat16(va * inv);
                    __hip_bfloat16 hb = __float2bfloat16(vb * inv);
                    o0.w[j] = *(ushort*)&ha;
                    o1.w[j] = *(ushort*)&hb;
                }
                __hip_bfloat16* dst =
                    Attnb + ((size_t)(b * SEQ + srow) * EMB) + h * HD + cb * 16;
                *(uint4*)(dst)     = o0.u;
                *(uint4*)(dst + 8) = o1.u;
            }
        }
    }
}

// ---------------------------------------------------------------------------
extern "C" void kernel_launch(void* const* d_in, const int* in_sizes, int n_in,
                              void* d_out, int out_size, void* d_ws, size_t ws_size,
                              hipStream_t stream) {
    const float* x  = (const float*)d_in[0];
    const float* Wq = (const float*)d_in[1];
    const float* Wk = (const float*)d_in[2];
    const float* Wv = (const float*)d_in[3];
    const float* Wo = (const float*)d_in[4];
    float* out = (float*)d_out;

    char* ws = (char*)d_ws;
    size_t off = 0;
    auto alloc = [&](size_t bytes) -> void* {
        void* p = ws + off;
        off += (bytes + 255) & ~(size_t)255;
        return p;
    };

    __hip_bfloat16* xb    = (__hip_bfloat16*)alloc((size_t)NX * 2);
    __hip_bfloat16* Wqkvb = (__hip_bfloat16*)alloc((size_t)NW * 3 * 2);
    __hip_bfloat16* Wob   = (__hip_bfloat16*)alloc((size_t)NW * 2);
    __hip_bfloat16* Qbuf  = (__hip_bfloat16*)alloc((size_t)NX * 2);
    __hip_bfloat16* Kbuf  = (__hip_bfloat16*)alloc((size_t)NX * 2);
    __hip_bfloat16* Vbuf  = (__hip_bfloat16*)alloc((size_t)NX * 2);
    __hip_bfloat16* Attnb = (__hip_bfloat16*)alloc((size_t)NX * 2);
    __hip_bfloat16* Opart = (__hip_bfloat16*)alloc((size_t)2 * 32 * SEQ * HD * 2);
    float*          Lpart = (float*)alloc((size_t)2 * 32 * SEQ * 4);
    float2*         ctab  = (float2*)alloc((size_t)SEQ * 32 * sizeof(float2));
    uint*           Flags = (uint*)alloc((size_t)512 * 4);

    // fused casts + RoPE table (256 tail blocks) + flag zeroing (1 block)
    fused_cast_kernel<<<(NX + 4 * NW) / (256 * 8) + 257, 256, 0, stream>>>(
        x, Wq, Wk, Wv, Wo, xb, Wqkvb, Wob, ctab, Flags);

    // fused QKV projection + RoPE epilogue (QSCALE folded into Q)
    dim3 qgrid(24, MROWS / 128);
    gemm_qkv_kernel<<<qgrid, 256, 0, stream>>>(xb, Wqkvb, Qbuf, Kbuf, Vbuf,
                                               ctab, MROWS, EMB);

    // S^T flash attention, balanced 2-way split + fused final write + fused
    // combine (atomic handshake)
    dim3 agrid(32, BATCH * NH);
    attn_mfma_kernel<<<agrid, 256, 0, stream>>>(Qbuf, Kbuf, Vbuf, Attnb,
                                                Opart, Lpart, Flags);

    // output projection -> fp32 d_out (128x64 tiles, 512 blocks)
    dim3 ggrid(EMB / 64, MROWS / 128);
    gemm_oproj_kernel<<<ggrid, 256, 0, stream>>>(Attnb, Wob, out, MROWS, EMB, EMB);
}

// Round 5
// 185.055 us; speedup vs baseline: 2.1039x; 2.1039x over previous
//
#include <hip/hip_runtime.h>
#include <hip/hip_bf16.h>

// Problem constants
#define BATCH 2
#define SEQ   2048
#define EMB   1024
#define NH    16
#define HD    64
#define MROWS (BATCH*SEQ)   // 4096
#define NX    (MROWS*EMB)   // 4194304
#define NW    (EMB*EMB)     // 1048576 = 2^20

using f32x4  = __attribute__((ext_vector_type(4))) float;
using bf16x8 = __attribute__((ext_vector_type(8))) short;

#define GLOBAL_AS(p) ((const __attribute__((address_space(1))) void*)(p))
#define LDS_AS(p)    ((__attribute__((address_space(3))) void*)(p))

#define ROPE_L2 0.4152410118609203f    // log2(10000)/32
#define QSCALE  0.045084220027780106f  // (1/sqrt(E)) * log2(e)

// ---------------------------------------------------------------------------
// Fused f32->bf16 cast of x and the 4 weight matrices (Wq,Wk,Wv stacked),
// PLUS (tail blocks) the RoPE cos/sin table: ctab[s][ip].
// ---------------------------------------------------------------------------
__global__ void fused_cast_kernel(const float* __restrict__ x,
                                  const float* __restrict__ Wq,
                                  const float* __restrict__ Wk,
                                  const float* __restrict__ Wv,
                                  const float* __restrict__ Wo,
                                  __hip_bfloat16* __restrict__ xb,
                                  __hip_bfloat16* __restrict__ Wqkvb,
                                  __hip_bfloat16* __restrict__ Wob,
                                  float2* __restrict__ ctab) {
    if (blockIdx.x >= 4096) {
        // RoPE table tail: one entry per thread
        int e  = (blockIdx.x - 4096) * 256 + threadIdx.x;   // [0, 65536)
        int s  = e >> 5;
        int ip = e & 31;
        float inv = exp2f(-(float)ip * ROPE_L2);
        float fr  = (float)s * inv;
        float2 cs;
        cs.x = cosf(fr);
        cs.y = sinf(fr);
        ctab[e] = cs;
        return;
    }
    size_t i8 = (size_t)(blockIdx.x * 256 + threadIdx.x) * 8;
    const float* src;
    __hip_bfloat16* dst;
    if (i8 < (size_t)NX) {
        src = x + i8;
        dst = xb + i8;
    } else {
        size_t w = i8 - NX;
        int which = (int)(w >> 20);
        size_t local = w & (NW - 1);
        if (which < 3) {
            src = (which == 0 ? Wq : (which == 1 ? Wk : Wv)) + local;
            dst = Wqkvb + w;
        } else {
            src = Wo + local;
            dst = Wob + local;
        }
    }
    float4 a = *(const float4*)(src);
    float4 b = *(const float4*)(src + 4);
    union { uint4 u; ushort s[8]; } o;
    const float* f = (const float*)&a;
#pragma unroll
    for (int j = 0; j < 4; ++j) {
        __hip_bfloat16 h = __float2bfloat16(f[j]);
        o.s[j] = *(ushort*)&h;
    }
    f = (const float*)&b;
#pragma unroll
    for (int j = 0; j < 4; ++j) {
        __hip_bfloat16 h = __float2bfloat16(f[j]);
        o.s[4 + j] = *(ushort*)&h;
    }
    *(uint4*)dst = o.u;
}

// ---------------------------------------------------------------------------
// Fused QKV GEMM: C[M,3072] = A[M,K] * Wqkv[3072,K]^T, routed to Q/K/V.
// 128x128 tile, BK=64, global_load_lds staging. grid (24,32) = 3 blocks/CU.
// T2 LDS swizzle (pre-swizzled gll SOURCE + XOR read; rule #21 involution).
// RoPE fused into the epilogue for Q/K outputs; Q scaled by QSCALE.
// ---------------------------------------------------------------------------
__global__ __launch_bounds__(256) void gemm_qkv_kernel(
        const __hip_bfloat16* __restrict__ A,
        const __hip_bfloat16* __restrict__ W,
        __hip_bfloat16* __restrict__ Qo,
        __hip_bfloat16* __restrict__ Ko,
        __hip_bfloat16* __restrict__ Vo,
        const float2* __restrict__ ctab, int M, int K) {
    __shared__ __hip_bfloat16 As[128 * 64];
    __shared__ __hip_bfloat16 Bs[128 * 64];

    const int tid  = threadIdx.x;
    const int wave = tid >> 6;
    const int lane = tid & 63;
    const int quad = lane >> 4;
    const int l16  = lane & 15;
    const int m0   = blockIdx.y * 128;
    const int n0   = blockIdx.x * 128;
    const int wm   = (wave >> 1) * 64;
    const int wn   = (wave & 1) * 64;
    const int xr   = l16 & 7;              // read-side XOR factor (row&7)

    f32x4 acc[4][4] = {};

    for (int k0 = 0; k0 < K; k0 += 64) {
#pragma unroll
        for (int it = 0; it < 4; ++it) {
            int flat = (wave * 4 + it) * 64 + lane;
            int row  = flat >> 3;
            int g    = (flat & 7) ^ (row & 7);   // inverse-swizzled source
            const __hip_bfloat16* ga = A + (size_t)(m0 + row) * K + k0 + g * 8;
            const __hip_bfloat16* gb = W + (size_t)(n0 + row) * K + k0 + g * 8;
            __builtin_amdgcn_global_load_lds(GLOBAL_AS(ga),
                LDS_AS(As + (size_t)(wave * 4 + it) * 512), 16, 0, 0);
            __builtin_amdgcn_global_load_lds(GLOBAL_AS(gb),
                LDS_AS(Bs + (size_t)(wave * 4 + it) * 512), 16, 0, 0);
        }
        __syncthreads();

#pragma unroll
        for (int kk = 0; kk < 2; ++kk) {
            const int kg = (kk * 4 + quad) ^ xr;   // swizzled read slot
            bf16x8 af[4], bfr[4];
#pragma unroll
            for (int i = 0; i < 4; ++i) {
                af[i]  = *(const bf16x8*)(&As[(wm + i * 16 + l16) * 64 + kg * 8]);
                bfr[i] = *(const bf16x8*)(&Bs[(wn + i * 16 + l16) * 64 + kg * 8]);
            }
#pragma unroll
            for (int i = 0; i < 4; ++i)
#pragma unroll
                for (int j = 0; j < 4; ++j)
                    acc[i][j] = __builtin_amdgcn_mfma_f32_16x16x32_bf16(
                        af[i], bfr[j], acc[i][j], 0, 0, 0);
        }
        __syncthreads();
    }

    const int tens = n0 >> 10;
    __hip_bfloat16* outp = (tens == 0) ? Qo : ((tens == 1) ? Ko : Vo);
    const int nbase = n0 & 1023;
    if (tens < 2) {
        // Q/K: apply RoPE on fp32 accumulators, then store (Q: * QSCALE)
        const float sgn   = (l16 & 1) ? 1.0f : -1.0f;   // odd: +, even: -
        const float qmul  = (tens == 0) ? QSCALE : 1.0f;
#pragma unroll
        for (int i = 0; i < 4; ++i)
#pragma unroll
            for (int j = 0; j < 4; ++j) {
                int col  = nbase + wn + j * 16 + l16;
                int ip   = ((wn + j * 16 + l16) & 63) >> 1;   // pair index [0,32)
                int row0 = m0 + wm + i * 16 + quad * 4;
#pragma unroll
                for (int rr = 0; rr < 4; ++rr) {
                    float v = acc[i][j][rr];
                    float p = __shfl_xor(v, 1);
                    int sp  = (row0 + rr) & (SEQ - 1);
                    float2 cs = ctab[sp * 32 + ip];
                    float o = (v * cs.x + sgn * p * cs.y) * qmul;
                    outp[(size_t)(row0 + rr) * EMB + col] = __float2bfloat16(o);
                }
            }
    } else {
#pragma unroll
        for (int i = 0; i < 4; ++i)
#pragma unroll
            for (int j = 0; j < 4; ++j) {
                int col  = nbase + wn + j * 16 + l16;
                int row0 = m0 + wm + i * 16 + quad * 4;
#pragma unroll
                for (int rr = 0; rr < 4; ++rr)
                    outp[(size_t)(row0 + rr) * EMB + col] = __float2bfloat16(acc[i][j][rr]);
            }
    }
}

// ---------------------------------------------------------------------------
// O-projection GEMM: C[M,N] = A[M,K] * B[N,K]^T, fp32 out.
// 128x64 tile -> grid (16,32) = 512 blocks = 2/CU. T2 swizzle as in qkv.
// ---------------------------------------------------------------------------
__global__ __launch_bounds__(256) void gemm_oproj_kernel(
        const __hip_bfloat16* __restrict__ A,
        const __hip_bfloat16* __restrict__ Bm,
        float* __restrict__ C, int M, int N, int K) {
    __shared__ __hip_bfloat16 As[128 * 64];
    __shared__ __hip_bfloat16 Bs[64 * 64];

    const int tid  = threadIdx.x;
    const int wave = tid >> 6;
    const int lane = tid & 63;
    const int quad = lane >> 4;
    const int l16  = lane & 15;
    const int m0   = blockIdx.y * 128;
    const int n0   = blockIdx.x * 64;
    const int wm   = (wave >> 1) * 64;
    const int wn   = (wave & 1) * 32;
    const int xr   = l16 & 7;

    f32x4 acc[4][2] = {};

    for (int k0 = 0; k0 < K; k0 += 64) {
#pragma unroll
        for (int it = 0; it < 4; ++it) {
            int flat = (wave * 4 + it) * 64 + lane;
            int row  = flat >> 3;
            int g    = (flat & 7) ^ (row & 7);
            const __hip_bfloat16* ga = A + (size_t)(m0 + row) * K + k0 + g * 8;
            __builtin_amdgcn_global_load_lds(GLOBAL_AS(ga),
                LDS_AS(As + (size_t)(wave * 4 + it) * 512), 16, 0, 0);
        }
#pragma unroll
        for (int it = 0; it < 2; ++it) {
            int flat = (wave * 2 + it) * 64 + lane;
            int row  = flat >> 3;
            int g    = (flat & 7) ^ (row & 7);
            const __hip_bfloat16* gb = Bm + (size_t)(n0 + row) * K + k0 + g * 8;
            __builtin_amdgcn_global_load_lds(GLOBAL_AS(gb),
                LDS_AS(Bs + (size_t)(wave * 2 + it) * 512), 16, 0, 0);
        }
        __syncthreads();

#pragma unroll
        for (int kk = 0; kk < 2; ++kk) {
            const int kg = (kk * 4 + quad) ^ xr;
            bf16x8 af[4], bfr[2];
#pragma unroll
            for (int i = 0; i < 4; ++i)
                af[i] = *(const bf16x8*)(&As[(wm + i * 16 + l16) * 64 + kg * 8]);
#pragma unroll
            for (int j = 0; j < 2; ++j)
                bfr[j] = *(const bf16x8*)(&Bs[(wn + j * 16 + l16) * 64 + kg * 8]);
#pragma unroll
            for (int i = 0; i < 4; ++i)
#pragma unroll
                for (int j = 0; j < 2; ++j)
                    acc[i][j] = __builtin_amdgcn_mfma_f32_16x16x32_bf16(
                        af[i], bfr[j], acc[i][j], 0, 0, 0);
        }
        __syncthreads();
    }

#pragma unroll
    for (int i = 0; i < 4; ++i)
#pragma unroll
        for (int j = 0; j < 2; ++j) {
            int col  = n0 + wn + j * 16 + l16;
            int row0 = m0 + wm + i * 16 + quad * 4;
#pragma unroll
            for (int rr = 0; rr < 4; ++rr)
                C[(size_t)(row0 + rr) * N + col] = acc[i][j][rr];
        }
}

// Single-instruction helpers (T12 recipe; no builtin for cvt_pk on gfx950)
__device__ inline uint cvt_pk_bf16(float lo, float hi) {
    uint r;
    asm("v_cvt_pk_bf16_f32 %0, %1, %2" : "=v"(r) : "v"(lo), "v"(hi));
    return r;
}
__device__ inline float exp2_raw(float x) {
    float r;
    asm("v_exp_f32 %0, %1" : "=v"(r) : "v"(x));
    return r;
}

// ---------------------------------------------------------------------------
// S^T flash attention (causal), fixed-base exp2 softmax (QSCALE*log2e in Q).
// S^T = K·Q^T (operand swap is free: A and B fragment layouts identical).
//
// v5: R4's fused combine REVERTED (device-scope __threadfence in 480 block
//     epilogues = chip-wide L2 writeback/invalidate storm -> 5x regression).
//     Separate combine_kernel restored. KEPT from R4 (clean VALU reductions):
//  * P-pack: v_cvt_pk_bf16_f32 (1 inst/pair, 8/iter) vs RNE emulation (~96).
//  * exp2: raw v_exp_f32; masked lanes (-16384) underflow to 0 correctly.
// v3 kept: row-sum via ones-MFMA, perm V^T pack, T5 setprio.
// v2 kept: register-resident P (k-slot permutation invariance), K direct
//     global->LDS with pre-swizzled source, K+V^T dbuf, 1 barrier/tile.
// Partition: grid (32, B*H) = 1024 blocks:
//   bx<16  (A, p=bx):    q-tile 31-p, k-tiles [0,17)       -> partial slot 0
//   bx>=16 (B, p=bx-16): q-tile 31-p, k-tiles [17, 31-p]   -> partial slot 1
//                        then q-tile p, k-tiles [0, p]     -> FINAL write
// ---------------------------------------------------------------------------
__global__ __launch_bounds__(256) void attn_mfma_kernel(
        const __hip_bfloat16* __restrict__ Qb,
        const __hip_bfloat16* __restrict__ Kb,
        const __hip_bfloat16* __restrict__ Vb,
        __hip_bfloat16* __restrict__ Attnb,
        __hip_bfloat16* __restrict__ Opart,
        float* __restrict__ Lpart) {
    const int bx   = blockIdx.x;
    const int bh   = blockIdx.y;
    const int b    = bh >> 4;
    const int h    = bh & (NH - 1);
    const int tid  = threadIdx.x;
    const int wave = tid >> 6;
    const int lane = tid & 63;
    const int quad = lane >> 4;
    const int l16  = lane & 15;

    __shared__ __hip_bfloat16 Ks[2][64 * 64];  // 16 KB, XOR col-swizzled, key-major
    __shared__ uint VTs[2][64][33];            // 16.5 KB, packed V^T pairs

    const int vtp = tid >> 3;                  // 0..31: key pair (V staging)
    const int sg  = tid & 7;                   // dim group  (V staging)
    const int lr  = lane >> 3;                 // gll: row within 8-row chunk
    const int lg  = (lane & 7) ^ lr;           // pre-swizzled source col group
    const size_t ksrc_lane = (size_t)lr * EMB + lg * 8;

    const __hip_bfloat16* Kbase = Kb + (size_t)b * SEQ * EMB + h * HD;
    const __hip_bfloat16* Vbase = Vb + (size_t)b * SEQ * EMB + h * HD;

    // B-operand of all-ones bf16 (1.0 = 0x3F80) for the row-sum MFMA
    union { uint u[4]; bf16x8 v; } onesu;
    onesu.u[0] = 0x3F803F80u; onesu.u[1] = 0x3F803F80u;
    onesu.u[2] = 0x3F803F80u; onesu.u[3] = 0x3F803F80u;
    const bf16x8 ones = onesu.v;

    const bool isA = (bx < 16);
    const int p   = isA ? bx : bx - 16;
    const int q0  = 31 - p;
    const int k00 = isA ? 0 : 17;
    const int n0s = isA ? 17 : (15 - p);
    const int q1  = p;
    const int n1s = isA ? 0 : (p + 1);

    for (int s = 0; s < 2; ++s) {
        const int qt = s ? q1 : q0;
        const int k0 = s ? 0 : k00;
        const int nt = s ? n1s : n0s;
        if (nt <= 0) continue;               // block-uniform
        const bool finalSeg = (!isA && s == 1);
        const int wrow = qt * 64 + wave * 16;

        // LDS handoff: previous segment's readers must finish before the
        // prologue gll below overwrites Ks[0]. Block-uniform path.
        __syncthreads();

        // Q fragments (B operand; layout identical to A): lane = q-row l16
        bf16x8 qf[2];
        {
            const __hip_bfloat16* qp =
                Qb + (size_t)(b * SEQ + wrow + l16) * EMB + h * HD + quad * 8;
            qf[0] = *(const bf16x8*)(qp);
            qf[1] = *(const bf16x8*)(qp + 32);
        }

        f32x4 of[4]  = {};       // O: col d = nb*16+l16, row q = quad*4+r
        f32x4 of_sum = {};       // L: row q = quad*4+r (all l16 identical)

        // prologue: stage tile k0 (V -> regs, K -> LDS buf0 via gll)
        const __hip_bfloat16* kgp = Kbase + (size_t)k0 * 64 * EMB;
        const __hip_bfloat16* vgp = Vbase + (size_t)(k0 * 64 + 2 * vtp) * EMB + sg * 8;
        uint4 vr0 = *(const uint4*)(vgp);
        uint4 vr1 = *(const uint4*)(vgp + EMB);
#pragma unroll
        for (int it = 0; it < 2; ++it)
            __builtin_amdgcn_global_load_lds(
                GLOBAL_AS(kgp + (size_t)(wave * 2 + it) * 8 * EMB + ksrc_lane),
                LDS_AS(&Ks[0][(wave * 2 + it) * 512]), 16, 0, 0);

        for (int i = 0; i < nt; ++i) {
            const int cur = i & 1;
            const int kt  = k0 + i;

            // V^T pack -> LDS: one v_perm_b32 per packed pair
            {
                const uint* v0u = (const uint*)&vr0;
                const uint* v1u = (const uint*)&vr1;
#pragma unroll
                for (int j = 0; j < 4; ++j) {
                    VTs[cur][sg * 8 + 2 * j][vtp] =
                        __builtin_amdgcn_perm(v1u[j], v0u[j], 0x05040100u);
                    VTs[cur][sg * 8 + 2 * j + 1][vtp] =
                        __builtin_amdgcn_perm(v1u[j], v0u[j], 0x07060302u);
                }
            }
            __syncthreads();     // drains gll(i): Ks[cur] + VTs[cur] ready

            if (i + 1 < nt) {    // stage tile i+1; drains at next barrier
                kgp += (size_t)64 * EMB;
                vgp += (size_t)64 * EMB;
                vr0 = *(const uint4*)(vgp);
                vr1 = *(const uint4*)(vgp + EMB);
#pragma unroll
                for (int it = 0; it < 2; ++it)
                    __builtin_amdgcn_global_load_lds(
                        GLOBAL_AS(kgp + (size_t)(wave * 2 + it) * 8 * EMB + ksrc_lane),
                        LDS_AS(&Ks[cur ^ 1][(wave * 2 + it) * 512]), 16, 0, 0);
            }

            // ---- S^T = K·Q^T: sc[mb] covers keys mb*16.. for q = wrow+l16 ----
            const bool diag = (kt == qt);
            const __hip_bfloat16* KsC = Ks[cur];
            f32x4 sc[4];
            __builtin_amdgcn_s_setprio(1);
#pragma unroll
            for (int mb = 0; mb < 4; ++mb) {
                f32x4 a = {};
                if (!(diag && mb > wave)) {
                    int krow = mb * 16 + l16;
#pragma unroll
                    for (int kb = 0; kb < 2; ++kb) {
                        int kg = (kb * 4 + quad) ^ (krow & 7);
                        bf16x8 kf = *(const bf16x8*)(&KsC[krow * 64 + kg * 8]);
                        a = __builtin_amdgcn_mfma_f32_16x16x32_bf16(kf, qf[kb], a, 0, 0, 0);
                    }
                }
                sc[mb] = a;
            }
            __builtin_amdgcn_s_setprio(0);

            // mask: key = mb*16+quad*4+r  vs  q = wave*16+l16 (local offsets)
            if (diag) {
#pragma unroll
                for (int mb = 0; mb < 4; ++mb)
#pragma unroll
                    for (int r = 0; r < 4; ++r)
                        if (mb * 16 + quad * 4 + r > wave * 16 + l16)
                            sc[mb][r] = -16384.0f;
            }

            // ---- p = 2^s via raw v_exp_f32 (row-sum via ones-MFMA below) ----
#pragma unroll
            for (int mb = 0; mb < 4; ++mb)
#pragma unroll
                for (int r = 0; r < 4; ++r)
                    sc[mb][r] = exp2_raw(sc[mb][r]);

            // ---- P stays in registers (k-permuted; matches V pair reads) ----
            bf16x8 pf[2];
            {
                union { uint u[4]; bf16x8 v; } t;
                t.u[0] = cvt_pk_bf16(sc[0][0], sc[0][1]);
                t.u[1] = cvt_pk_bf16(sc[0][2], sc[0][3]);
                t.u[2] = cvt_pk_bf16(sc[1][0], sc[1][1]);
                t.u[3] = cvt_pk_bf16(sc[1][2], sc[1][3]);
                pf[0] = t.v;
                t.u[0] = cvt_pk_bf16(sc[2][0], sc[2][1]);
                t.u[1] = cvt_pk_bf16(sc[2][2], sc[2][3]);
                t.u[2] = cvt_pk_bf16(sc[3][0], sc[3][1]);
                t.u[3] = cvt_pk_bf16(sc[3][2], sc[3][3]);
                pf[1] = t.v;
            }

            // ---- O += P V ; L += P 1 (row-sum on the matrix pipe) ----
            const uint* VT0 = &VTs[cur][0][0];
            __builtin_amdgcn_s_setprio(1);
#pragma unroll
            for (int nb = 0; nb < 4; ++nb) {
                const uint* vrow = VT0 + (size_t)(nb * 16 + l16) * 33;
#pragma unroll
                for (int c = 0; c < 2; ++c) {
                    union { uint u[4]; bf16x8 v; } vf;
                    vf.u[0] = vrow[c * 16 + 2 * quad];
                    vf.u[1] = vrow[c * 16 + 2 * quad + 1];
                    vf.u[2] = vrow[c * 16 + 8 + 2 * quad];
                    vf.u[3] = vrow[c * 16 + 8 + 2 * quad + 1];
                    of[nb] = __builtin_amdgcn_mfma_f32_16x16x32_bf16(
                        pf[c], vf.v, of[nb], 0, 0, 0);
                }
            }
            of_sum = __builtin_amdgcn_mfma_f32_16x16x32_bf16(pf[0], ones, of_sum, 0, 0, 0);
            of_sum = __builtin_amdgcn_mfma_f32_16x16x32_bf16(pf[1], ones, of_sum, 0, 0, 0);
            __builtin_amdgcn_s_setprio(0);
        }

        // ---- segment epilogue: of_sum[r] = L[q = quad*4 + r] directly ----
        const int rl0 = quad * 4;            // local output row base within wave tile
        if (finalSeg) {
            float linv[4];
#pragma unroll
            for (int r = 0; r < 4; ++r)
                linv[r] = 1.0f / of_sum[r];
#pragma unroll
            for (int nb = 0; nb < 4; ++nb)
#pragma unroll
                for (int r = 0; r < 4; ++r) {
                    float v = of[nb][r] * linv[r];
                    Attnb[(size_t)(b * SEQ + wrow + rl0 + r) * EMB + h * HD + nb * 16 + l16] =
                        __float2bfloat16(v);
                }
        } else {
            const int slot = isA ? 0 : 1;
            const size_t lbase = ((size_t)slot * 32 + bh) * SEQ + wrow;
            if (l16 == 0) {
#pragma unroll
                for (int r = 0; r < 4; ++r)
                    Lpart[lbase + rl0 + r] = of_sum[r];
            }
#pragma unroll
            for (int nb = 0; nb < 4; ++nb)
#pragma unroll
                for (int r = 0; r < 4; ++r)
                    Opart[(lbase + rl0 + r) * HD + nb * 16 + l16] =
                        __float2bfloat16(of[nb][r]);
        }
    }
}

// ---------------------------------------------------------------------------
// Combine partials for heavy rows (s >= 1024, qt 16..31):
// out = (O0 + O1?) / (l0 + l1?). Slot 1 exists only for qt >= 17.
// ---------------------------------------------------------------------------
__global__ void combine_kernel(const __hip_bfloat16* __restrict__ Opart,
                               const float* __restrict__ Lpart,
                               __hip_bfloat16* __restrict__ Attnb) {
    int idx = blockIdx.x * 256 + threadIdx.x;   // 262144 total
    int d8 = idx & 7;
    int s  = 1024 + ((idx >> 3) & 1023);        // heavy rows only
    int bh = idx >> 13;
    int b  = bh >> 4;
    int h  = bh & (NH - 1);
    int qt = s >> 6;                            // 16..31

    size_t base0 = ((size_t)bh * SEQ + s) * HD + d8 * 8;
    bf16x8 o0 = *(const bf16x8*)(Opart + base0);
    float l = Lpart[(size_t)bh * SEQ + s];
    float acc[8];
#pragma unroll
    for (int j = 0; j < 8; ++j)
        acc[j] = __uint_as_float(((uint)(ushort)o0[j]) << 16);
    if (qt >= 17) {
        size_t base1 = ((size_t)(32 + bh) * SEQ + s) * HD + d8 * 8;
        bf16x8 o1 = *(const bf16x8*)(Opart + base1);
        l += Lpart[(size_t)(32 + bh) * SEQ + s];
#pragma unroll
        for (int j = 0; j < 8; ++j)
            acc[j] += __uint_as_float(((uint)(ushort)o1[j]) << 16);
    }
    float inv = 1.0f / l;
    union { uint4 u; ushort w[8]; } o;
#pragma unroll
    for (int j = 0; j < 8; ++j) {
        __hip_bfloat16 hv = __float2bfloat16(acc[j] * inv);
        o.w[j] = *(ushort*)&hv;
    }
    *(uint4*)(Attnb + ((size_t)(b * SEQ + s) * EMB) + h * HD + d8 * 8) = o.u;
}

// ---------------------------------------------------------------------------
extern "C" void kernel_launch(void* const* d_in, const int* in_sizes, int n_in,
                              void* d_out, int out_size, void* d_ws, size_t ws_size,
                              hipStream_t stream) {
    const float* x  = (const float*)d_in[0];
    const float* Wq = (const float*)d_in[1];
    const float* Wk = (const float*)d_in[2];
    const float* Wv = (const float*)d_in[3];
    const float* Wo = (const float*)d_in[4];
    float* out = (float*)d_out;

    char* ws = (char*)d_ws;
    size_t off = 0;
    auto alloc = [&](size_t bytes) -> void* {
        void* p = ws + off;
        off += (bytes + 255) & ~(size_t)255;
        return p;
    };

    __hip_bfloat16* xb    = (__hip_bfloat16*)alloc((size_t)NX * 2);
    __hip_bfloat16* Wqkvb = (__hip_bfloat16*)alloc((size_t)NW * 3 * 2);
    __hip_bfloat16* Wob   = (__hip_bfloat16*)alloc((size_t)NW * 2);
    __hip_bfloat16* Qbuf  = (__hip_bfloat16*)alloc((size_t)NX * 2);
    __hip_bfloat16* Kbuf  = (__hip_bfloat16*)alloc((size_t)NX * 2);
    __hip_bfloat16* Vbuf  = (__hip_bfloat16*)alloc((size_t)NX * 2);
    __hip_bfloat16* Attnb = (__hip_bfloat16*)alloc((size_t)NX * 2);
    __hip_bfloat16* Opart = (__hip_bfloat16*)alloc((size_t)2 * 32 * SEQ * HD * 2);
    float*          Lpart = (float*)alloc((size_t)2 * 32 * SEQ * 4);
    float2*         ctab  = (float2*)alloc((size_t)SEQ * 32 * sizeof(float2));

    // fused casts + RoPE table (256 tail blocks)
    fused_cast_kernel<<<(NX + 4 * NW) / (256 * 8) + 256, 256, 0, stream>>>(
        x, Wq, Wk, Wv, Wo, xb, Wqkvb, Wob, ctab);

    // fused QKV projection + RoPE epilogue (QSCALE folded into Q)
    dim3 qgrid(24, MROWS / 128);
    gemm_qkv_kernel<<<qgrid, 256, 0, stream>>>(xb, Wqkvb, Qbuf, Kbuf, Vbuf,
                                               ctab, MROWS, EMB);

    // S^T flash attention, balanced 2-way split + fused final write
    dim3 agrid(32, BATCH * NH);
    attn_mfma_kernel<<<agrid, 256, 0, stream>>>(Qbuf, Kbuf, Vbuf, Attnb,
                                                Opart, Lpart);

    // combine partials for heavy q-tiles
    combine_kernel<<<(32 * 1024 * 8) / 256, 256, 0, stream>>>(Opart, Lpart, Attnb);

    // output projection -> fp32 d_out (128x64 tiles, 512 blocks)
    dim3 ggrid(EMB / 64, MROWS / 128);
    gemm_oproj_kernel<<<ggrid, 256, 0, stream>>>(Attnb, Wob, out, MROWS, EMB, EMB);
}